// Round 8
// baseline (512.558 us; speedup 1.0000x reference)
//
#include <hip/hip_runtime.h>

// Problem dims (fixed by setup_inputs)
#define HH 384
#define WW 512
#define NB 4
#define HWP (HH * WW)       // 196608
#define NPIX (NB * HWP)     // 786432
#define SH 96
#define SW 128
#define SHW (SH * SW)

// Strict-IEEE f32 bilinear 4x upsample of (10*flow) — bit-identical to the
// passing round-3 version. Do not touch: floor decisions depend on it.
static __device__ __forceinline__ float upsample_flow_f32(const float* __restrict__ f, int y, int x) {
    float sx = __fadd_rn(__fmul_rn((float)x, 0.25f), -0.375f);  // exact
    float sy = __fadd_rn(__fmul_rn((float)y, 0.25f), -0.375f);  // exact
    float fx0 = floorf(sx), fy0 = floorf(sy);
    float wx = __fsub_rn(sx, fx0);   // exact: {0.625,0.875,0.125,0.375}
    float wy = __fsub_rn(sy, fy0);
    int ix = (int)fx0, iy = (int)fy0;
    int x0 = max(ix, 0), x1 = min(ix + 1, SW - 1);
    int y0 = max(iy, 0), y1 = min(iy + 1, SH - 1);
    float v00 = __fmul_rn(10.0f, f[y0 * SW + x0]);
    float v01 = __fmul_rn(10.0f, f[y0 * SW + x1]);
    float v10 = __fmul_rn(10.0f, f[y1 * SW + x0]);
    float v11 = __fmul_rn(10.0f, f[y1 * SW + x1]);
    float omx = __fsub_rn(1.0f, wx);
    float omy = __fsub_rn(1.0f, wy);
    float w00 = __fmul_rn(omx, omy);
    float w10 = __fmul_rn(wx, omy);
    float w01 = __fmul_rn(omx, wy);
    float w11 = __fmul_rn(wx, wy);
    float s = __fmul_rn(w00, v00);
    s = __fadd_rn(s, __fmul_rn(w10, v01));
    s = __fadd_rn(s, __fmul_rn(w01, v10));
    s = __fadd_rn(s, __fmul_rn(w11, v11));
    return s;
}

// Histogram scatter: ONE deposit per source at (xf,yf). Both sides in one
// dispatch (blockIdx.y = side) — planar per-side G arrays are fully disjoint.
__global__ void scatter_k(const float* __restrict__ flow01, const float* __restrict__ flow10,
                          float* __restrict__ g0, float* __restrict__ g1) {
    int idx = blockIdx.x * blockDim.x + threadIdx.x;
    if (idx >= NPIX) return;
    const float* flow = blockIdx.y ? flow10 : flow01;
    float* G = blockIdx.y ? g1 : g0;
    int x = idx % WW;
    int y = (idx / WW) % HH;
    int b = idx / HWP;
    const float* fp = flow + b * 2 * SHW;
    float fx = upsample_flow_f32(fp, y, x);
    float fy = upsample_flow_f32(fp + SHW, y, x);
    float x2 = __fadd_rn((float)x, fx);
    float y2 = __fadd_rn((float)y, fy);
    if (x2 >= 0.0f && x2 <= (float)(WW - 1) && y2 >= 0.0f && y2 <= (float)(HH - 1)) {
        int xf = (int)floorf(x2);   // in [0, W-1]
        int yf = (int)floorf(y2);   // in [0, H-1]
        int o = b * HWP + yf * WW + xf;
        unsafeAtomicAdd(G + o, -fx);
        unsafeAtomicAdd(G + NPIX + o, -fy);
        unsafeAtomicAdd(G + 2 * NPIX + o, 1.0f);
    }
}

// 2x2 weighted box-sum of G == the reference's 4-neighbor scatter result.
// Edge weights: col 0 sees only G(0); col W-1 sees G(W-2) + 2*G(W-1)
// (clipped xf=W-1 deposits twice). Same in y. Weights are exact {1,2,4}.
static __device__ __forceinline__ void box_sum(const float* __restrict__ G, int b, int y, int x,
                                               float& ax, float& ay, float& c) {
    const float* Gx = G;
    const float* Gy = G + NPIX;
    const float* Gc = G + 2 * NPIX;
    float wxs1 = (x == WW - 1) ? 2.0f : 1.0f;
    float wys1 = (y == HH - 1) ? 2.0f : 1.0f;
    float sx = 0.0f, sy = 0.0f, sc = 0.0f;
    int base = b * HWP;
    #pragma unroll
    for (int j = 0; j < 2; j++) {
        int ey = y - 1 + j;
        if (ey < 0) continue;
        float wy = j ? wys1 : 1.0f;
        #pragma unroll
        for (int i = 0; i < 2; i++) {
            int ex = x - 1 + i;
            if (ex < 0) continue;
            float w = wy * ((i ? wxs1 : 1.0f));   // exact
            int o = base + ey * WW + ex;
            sx += w * Gx[o];
            sy += w * Gy[o];
            sc += w * Gc[o];
        }
    }
    ax = sx; ay = sy; c = sc;
}

// Compute Ft(x,y) inline: box-sum avg + rare hole-fill (P(hole) ~ e^-4).
static __device__ __forceinline__ void flow_at(const float* __restrict__ G, int b, int y, int x,
                                               float& ofx, float& ofy) {
    float ax, ay, c;
    box_sum(G, b, y, x, ax, ay, c);
    if (c > 0.0f) {
        ofx = ax / c;
        ofy = ay / c;
    } else {
        float nx = 0.0f, ny = 0.0f, den = 0.0f;
        float bx, by, bc;
        if (y > 0)      { box_sum(G, b, y - 1, x, bx, by, bc); if (bc > 0.0f) { nx += bx / bc; ny += by / bc; den += 1.0f; } }
        if (y < HH - 1) { box_sum(G, b, y + 1, x, bx, by, bc); if (bc > 0.0f) { nx += bx / bc; ny += by / bc; den += 1.0f; } }
        if (x > 0)      { box_sum(G, b, y, x - 1, bx, by, bc); if (bc > 0.0f) { nx += bx / bc; ny += by / bc; den += 1.0f; } }
        if (x < WW - 1) { box_sum(G, b, y, x + 1, bx, by, bc); if (bc > 0.0f) { nx += bx / bc; ny += by / bc; den += 1.0f; } }
        float inv = 1.0f / fmaxf(den, 1.0f);
        ofx = nx * inv;
        ofy = ny * inv;
    }
}

// Filter interpolation fused with flow-projection read-out (fill inline).
// One side per block (blockIdx.z = side*NB + b), 1 pixel/thread (R6-proven).
// Results combined via atomicAdd into memset-zeroed out.
__global__ void interp_k(const float* __restrict__ img0, const float* __restrict__ img2,
                         const float* __restrict__ filt0, const float* __restrict__ filt1,
                         const float* __restrict__ g0, const float* __restrict__ g1,
                         float* __restrict__ out) {
    int x = blockIdx.x * 64 + threadIdx.x;
    int y = blockIdx.y * 4 + threadIdx.y;
    int bz = blockIdx.z;
    int side = bz >> 2;          // NB == 4
    int b = bz & 3;
    const float* img  = side ? img2  : img0;
    const float* filt = side ? filt1 : filt0;
    const float* G    = side ? g1 : g0;

    float fx, fy;
    flow_at(G, b, y, x, fx, fy);

    float x2 = fminf(fmaxf((float)x + fx, 0.0f), (float)(WW - 1));
    float y2 = fminf(fmaxf((float)y + fy, 0.0f), (float)(HH - 1));
    float xff = floorf(x2), yff = floorf(y2);
    int xf = (int)xff, yf = (int)yff;
    float a  = x2 - xff;
    float bb = y2 - yff;
    float w00 = (1.0f - a) * (1.0f - bb);
    float w10 = a * (1.0f - bb);
    float w01 = (1.0f - a) * bb;
    float w11 = a * bb;

    // load 4x4 filter taps for this pixel (coalesced per plane)
    float F[4][4];
    #pragma unroll
    for (int k = 0; k < 16; k++) {
        F[k >> 2][k & 3] = filt[((b * 16 + k) * HH + y) * WW + x];
    }
    // fold bilinear weights into a 5x5 effective coefficient map
    float Cf[5][5];
    #pragma unroll
    for (int r = 0; r < 5; r++) {
        #pragma unroll
        for (int sc = 0; sc < 5; sc++) {
            float v = 0.0f;
            if (r < 4 && sc < 4)   v += w00 * F[r][sc];
            if (r < 4 && sc >= 1)  v += w10 * F[r][sc - 1];
            if (r >= 1 && sc < 4)  v += w01 * F[r - 1][sc];
            if (r >= 1 && sc >= 1) v += w11 * F[r - 1][sc - 1];
            Cf[r][sc] = v;
        }
    }
    int rows[5], cols[5];
    #pragma unroll
    for (int r = 0; r < 5; r++) rows[r] = min(max(yf - 1 + r, 0), HH - 1);
    #pragma unroll
    for (int sc = 0; sc < 5; sc++) cols[sc] = min(max(xf - 1 + sc, 0), WW - 1);
    #pragma unroll
    for (int c = 0; c < 3; c++) {
        const float* ip = img + (b * 3 + c) * HWP;
        float accv = 0.0f;
        #pragma unroll
        for (int r = 0; r < 5; r++) {
            const float* rp = ip + rows[r] * WW;
            #pragma unroll
            for (int sc = 0; sc < 5; sc++) {
                accv += Cf[r][sc] * rp[cols[sc]];
            }
        }
        unsafeAtomicAdd(&out[((b * 3 + c) * HH + y) * WW + x], 0.5f * accv);
    }
}

extern "C" void kernel_launch(void* const* d_in, const int* in_sizes, int n_in,
                              void* d_out, int out_size, void* d_ws, size_t ws_size,
                              hipStream_t stream) {
    const float* input0 = (const float*)d_in[0];
    const float* input2 = (const float*)d_in[1];
    const float* flow01 = (const float*)d_in[2];
    const float* flow10 = (const float*)d_in[3];
    const float* filt0  = (const float*)d_in[4];
    const float* filt1  = (const float*)d_in[5];
    float* out = (float*)d_out;

    float* ws = (float*)d_ws;
    float* g0   = ws;                    // 3*NPIX: Gx, Gy, Gc (side 0)
    float* g1   = ws + 3 * NPIX;         // 3*NPIX (side 1)

    // zero both histogram regions (contiguous) and the output (atomic combine)
    hipMemsetAsync(g0, 0, (size_t)6 * NPIX * sizeof(float), stream);
    hipMemsetAsync(out, 0, (size_t)3 * NPIX * sizeof(float), stream);

    const int BS = 256;
    const int NBLK = (NPIX + BS - 1) / BS;

    scatter_k<<<dim3(NBLK, 2), BS, 0, stream>>>(flow01, flow10, g0, g1);
    interp_k<<<dim3(WW / 64, HH / 4, NB * 2), dim3(64, 4), 0, stream>>>(
        input0, input2, filt0, filt1, g0, g1, out);
}

// Round 9
// 383.457 us; speedup vs baseline: 1.3367x; 1.3367x over previous
//
#include <hip/hip_runtime.h>

// Problem dims (fixed by setup_inputs)
#define HH 384
#define WW 512
#define NB 4
#define HWP (HH * WW)       // 196608
#define NPIX (NB * HWP)     // 786432
#define SH 96
#define SW 128
#define SHW (SH * SW)

// Strict-IEEE f32 bilinear 4x upsample of (10*flow) — bit-identical to the
// passing round-3 version. Do not touch: floor decisions depend on it.
static __device__ __forceinline__ float upsample_flow_f32(const float* __restrict__ f, int y, int x) {
    float sx = __fadd_rn(__fmul_rn((float)x, 0.25f), -0.375f);  // exact
    float sy = __fadd_rn(__fmul_rn((float)y, 0.25f), -0.375f);  // exact
    float fx0 = floorf(sx), fy0 = floorf(sy);
    float wx = __fsub_rn(sx, fx0);   // exact: {0.625,0.875,0.125,0.375}
    float wy = __fsub_rn(sy, fy0);
    int ix = (int)fx0, iy = (int)fy0;
    int x0 = max(ix, 0), x1 = min(ix + 1, SW - 1);
    int y0 = max(iy, 0), y1 = min(iy + 1, SH - 1);
    float v00 = __fmul_rn(10.0f, f[y0 * SW + x0]);
    float v01 = __fmul_rn(10.0f, f[y0 * SW + x1]);
    float v10 = __fmul_rn(10.0f, f[y1 * SW + x0]);
    float v11 = __fmul_rn(10.0f, f[y1 * SW + x1]);
    float omx = __fsub_rn(1.0f, wx);
    float omy = __fsub_rn(1.0f, wy);
    float w00 = __fmul_rn(omx, omy);
    float w10 = __fmul_rn(wx, omy);
    float w01 = __fmul_rn(omx, wy);
    float w11 = __fmul_rn(wx, wy);
    float s = __fmul_rn(w00, v00);
    s = __fadd_rn(s, __fmul_rn(w10, v01));
    s = __fadd_rn(s, __fmul_rn(w01, v10));
    s = __fadd_rn(s, __fmul_rn(w11, v11));
    return s;
}

// Histogram scatter: ONE deposit per source at (xf,yf). Both sides in one
// dispatch (blockIdx.y = side) — planar per-side G arrays are fully disjoint.
__global__ void scatter_k(const float* __restrict__ flow01, const float* __restrict__ flow10,
                          float* __restrict__ g0, float* __restrict__ g1) {
    int idx = blockIdx.x * blockDim.x + threadIdx.x;
    if (idx >= NPIX) return;
    const float* flow = blockIdx.y ? flow10 : flow01;
    float* G = blockIdx.y ? g1 : g0;
    int x = idx % WW;
    int y = (idx / WW) % HH;
    int b = idx / HWP;
    const float* fp = flow + b * 2 * SHW;
    float fx = upsample_flow_f32(fp, y, x);
    float fy = upsample_flow_f32(fp + SHW, y, x);
    float x2 = __fadd_rn((float)x, fx);
    float y2 = __fadd_rn((float)y, fy);
    if (x2 >= 0.0f && x2 <= (float)(WW - 1) && y2 >= 0.0f && y2 <= (float)(HH - 1)) {
        int xf = (int)floorf(x2);   // in [0, W-1]
        int yf = (int)floorf(y2);   // in [0, H-1]
        int o = b * HWP + yf * WW + xf;
        unsafeAtomicAdd(G + o, -fx);
        unsafeAtomicAdd(G + NPIX + o, -fy);
        unsafeAtomicAdd(G + 2 * NPIX + o, 1.0f);
    }
}

// 2x2 weighted box-sum of G == the reference's 4-neighbor scatter result.
// Edge weights: col 0 sees only G(0); col W-1 sees G(W-2) + 2*G(W-1)
// (clipped xf=W-1 deposits twice). Same in y. Weights are exact {1,2,4}.
static __device__ __forceinline__ void box_sum(const float* __restrict__ G, int b, int y, int x,
                                               float& ax, float& ay, float& c) {
    const float* Gx = G;
    const float* Gy = G + NPIX;
    const float* Gc = G + 2 * NPIX;
    float wxs1 = (x == WW - 1) ? 2.0f : 1.0f;
    float wys1 = (y == HH - 1) ? 2.0f : 1.0f;
    float sx = 0.0f, sy = 0.0f, sc = 0.0f;
    int base = b * HWP;
    #pragma unroll
    for (int j = 0; j < 2; j++) {
        int ey = y - 1 + j;
        if (ey < 0) continue;
        float wy = j ? wys1 : 1.0f;
        #pragma unroll
        for (int i = 0; i < 2; i++) {
            int ex = x - 1 + i;
            if (ex < 0) continue;
            float w = wy * ((i ? wxs1 : 1.0f));   // exact
            int o = base + ey * WW + ex;
            sx += w * Gx[o];
            sy += w * Gy[o];
            sc += w * Gc[o];
        }
    }
    ax = sx; ay = sy; c = sc;
}

// Fused box-sum + avg + hole fill, both sides in one dispatch.
// Ft layout = [Ftx | Fty].
__global__ void fill2_k(const float* __restrict__ g0, const float* __restrict__ g1,
                        float* __restrict__ Ft0, float* __restrict__ Ft2) {
    int idx = blockIdx.x * blockDim.x + threadIdx.x;
    if (idx >= NPIX) return;
    int side = blockIdx.y;
    const float* G = side ? g1 : g0;
    float* Ft = side ? Ft2 : Ft0;
    int x = idx % WW;
    int y = (idx / WW) % HH;
    int b = idx / HWP;
    float ax, ay, c;
    box_sum(G, b, y, x, ax, ay, c);
    float ox, oy;
    if (c > 0.0f) {
        ox = ax / c;
        oy = ay / c;
    } else {
        float nx = 0.0f, ny = 0.0f, den = 0.0f;
        float bx, by, bc;
        if (y > 0)      { box_sum(G, b, y - 1, x, bx, by, bc); if (bc > 0.0f) { nx += bx / bc; ny += by / bc; den += 1.0f; } }
        if (y < HH - 1) { box_sum(G, b, y + 1, x, bx, by, bc); if (bc > 0.0f) { nx += bx / bc; ny += by / bc; den += 1.0f; } }
        if (x > 0)      { box_sum(G, b, y, x - 1, bx, by, bc); if (bc > 0.0f) { nx += bx / bc; ny += by / bc; den += 1.0f; } }
        if (x < WW - 1) { box_sum(G, b, y, x + 1, bx, by, bc); if (bc > 0.0f) { nx += bx / bc; ny += by / bc; den += 1.0f; } }
        float inv = 1.0f / fmaxf(den, 1.0f);
        ox = nx * inv;
        oy = ny * inv;
    }
    Ft[idx] = ox;
    Ft[NPIX + idx] = oy;
}

// Filter interpolation, one side per block (blockIdx.z = side*NB + b),
// 1 pixel/thread, 64x4 tile (R6-proven). Interior pixels load each 5-float
// gather row as ONE 20B memcpy (dwordx4+dword) instead of 5 scalar loads:
// 93 -> ~48 VMEM ops per thread in a latency-bound kernel.
__global__ void interp_k(const float* __restrict__ img0, const float* __restrict__ img2,
                         const float* __restrict__ filt0, const float* __restrict__ filt1,
                         const float* __restrict__ Ft0, const float* __restrict__ Ft2,
                         float* __restrict__ out) {
    int x = blockIdx.x * 64 + threadIdx.x;
    int y = blockIdx.y * 4 + threadIdx.y;
    int bz = blockIdx.z;
    int side = bz >> 2;          // NB == 4
    int b = bz & 3;
    const float* img  = side ? img2  : img0;
    const float* filt = side ? filt1 : filt0;
    const float* Ft   = side ? Ft2   : Ft0;

    int idx = b * HWP + y * WW + x;
    float fx = Ft[idx];
    float fy = Ft[NPIX + idx];
    float x2 = fminf(fmaxf((float)x + fx, 0.0f), (float)(WW - 1));
    float y2 = fminf(fmaxf((float)y + fy, 0.0f), (float)(HH - 1));
    float xff = floorf(x2), yff = floorf(y2);
    int xf = (int)xff, yf = (int)yff;
    float a  = x2 - xff;
    float bb = y2 - yff;
    float w00 = (1.0f - a) * (1.0f - bb);
    float w10 = a * (1.0f - bb);
    float w01 = (1.0f - a) * bb;
    float w11 = a * bb;

    // load 4x4 filter taps for this pixel (coalesced per plane)
    float F[4][4];
    #pragma unroll
    for (int k = 0; k < 16; k++) {
        F[k >> 2][k & 3] = filt[((b * 16 + k) * HH + y) * WW + x];
    }
    // fold bilinear weights into a 5x5 effective coefficient map
    float Cf[5][5];
    #pragma unroll
    for (int r = 0; r < 5; r++) {
        #pragma unroll
        for (int sc = 0; sc < 5; sc++) {
            float v = 0.0f;
            if (r < 4 && sc < 4)   v += w00 * F[r][sc];
            if (r < 4 && sc >= 1)  v += w10 * F[r][sc - 1];
            if (r >= 1 && sc < 4)  v += w01 * F[r - 1][sc];
            if (r >= 1 && sc >= 1) v += w11 * F[r - 1][sc - 1];
            Cf[r][sc] = v;
        }
    }
    int rows[5];
    #pragma unroll
    for (int r = 0; r < 5; r++) rows[r] = min(max(yf - 1 + r, 0), HH - 1);

    bool interior = (xf >= 1) && (xf <= WW - 4);
    if (interior) {
        int x0 = xf - 1;   // cols are x0..x0+4, all in-bounds
        #pragma unroll
        for (int c = 0; c < 3; c++) {
            const float* ip = img + (b * 3 + c) * HWP;
            float accv = 0.0f;
            #pragma unroll
            for (int r = 0; r < 5; r++) {
                const float* rp = ip + rows[r] * WW + x0;
                float wrow[5];
                __builtin_memcpy(wrow, rp, 5 * sizeof(float));
                #pragma unroll
                for (int sc = 0; sc < 5; sc++) {
                    accv += Cf[r][sc] * wrow[sc];
                }
            }
            unsafeAtomicAdd(&out[((b * 3 + c) * HH + y) * WW + x], 0.5f * accv);
        }
    } else {
        int cols[5];
        #pragma unroll
        for (int sc = 0; sc < 5; sc++) cols[sc] = min(max(xf - 1 + sc, 0), WW - 1);
        #pragma unroll
        for (int c = 0; c < 3; c++) {
            const float* ip = img + (b * 3 + c) * HWP;
            float accv = 0.0f;
            #pragma unroll
            for (int r = 0; r < 5; r++) {
                const float* rp = ip + rows[r] * WW;
                #pragma unroll
                for (int sc = 0; sc < 5; sc++) {
                    accv += Cf[r][sc] * rp[cols[sc]];
                }
            }
            unsafeAtomicAdd(&out[((b * 3 + c) * HH + y) * WW + x], 0.5f * accv);
        }
    }
}

extern "C" void kernel_launch(void* const* d_in, const int* in_sizes, int n_in,
                              void* d_out, int out_size, void* d_ws, size_t ws_size,
                              hipStream_t stream) {
    const float* input0 = (const float*)d_in[0];
    const float* input2 = (const float*)d_in[1];
    const float* flow01 = (const float*)d_in[2];
    const float* flow10 = (const float*)d_in[3];
    const float* filt0  = (const float*)d_in[4];
    const float* filt1  = (const float*)d_in[5];
    float* out = (float*)d_out;

    float* ws = (float*)d_ws;
    float* g0   = ws;                    // 3*NPIX: Gx, Gy, Gc (side 0)
    float* g1   = ws + 3 * NPIX;         // 3*NPIX (side 1)
    float* Ft0  = ws + 6 * NPIX;         // 2*NPIX: Ftx, Fty
    float* Ft2  = ws + 8 * NPIX;         // 2*NPIX

    // zero both histogram regions (contiguous) and the output (atomic combine)
    hipMemsetAsync(g0, 0, (size_t)6 * NPIX * sizeof(float), stream);
    hipMemsetAsync(out, 0, (size_t)3 * NPIX * sizeof(float), stream);

    const int BS = 256;
    const int NBLK = (NPIX + BS - 1) / BS;

    scatter_k<<<dim3(NBLK, 2), BS, 0, stream>>>(flow01, flow10, g0, g1);
    fill2_k<<<dim3(NBLK, 2), BS, 0, stream>>>(g0, g1, Ft0, Ft2);
    interp_k<<<dim3(WW / 64, HH / 4, NB * 2), dim3(64, 4), 0, stream>>>(
        input0, input2, filt0, filt1, Ft0, Ft2, out);
}